// Round 12
// baseline (278.424 us; speedup 1.0000x reference)
//
#include <hip/hip_runtime.h>

static constexpr int NN = 100000;   // nodes
static constexpr int NE = 3200000;  // edges
static constexpr int DI = 128;
static constexpr int DH = 64;
static constexpr int DO = 32;

static constexpr int NBK  = 391;    // dst buckets (dst>>8), 391*256 >= NN
static constexpr int BCAP = 9216;   // per-bucket capacity (mean 8184, +11 sigma)
static constexpr int TILE = 4096;   // edges per block in bucket pass (LDS 28.8KB)
static constexpr int NBT  = (NE + TILE - 1) / TILE;  // 782 bucket-role blocks
static constexpr int XW1_BASE = NBT + 1;             // 783
static constexpr int XW1_BLOCKS = (NN + 63) / 64;    // 1563

typedef short short8 __attribute__((ext_vector_type(8)));  // MFMA A/B frag
typedef float f32x4  __attribute__((ext_vector_type(4)));  // MFMA C/D frag

__device__ __forceinline__ unsigned short f2bf(float f) {
    union { float f; unsigned u; } v; v.f = f;
    unsigned r = v.u + 0x7FFFu + ((v.u >> 16) & 1u);  // RNE
    return (unsigned short)(r >> 16);
}
__device__ __forceinline__ float bflo(unsigned u) {
    union { unsigned u; float f; } v; v.u = u << 16; return v.f;
}
__device__ __forceinline__ float bfhi(unsigned u) {
    union { unsigned u; float f; } v; v.u = u & 0xFFFF0000u; return v.f;
}
// accumulate 8 bf16 features (one uint4) scaled by d into s[0..7]
__device__ __forceinline__ void acc_row8(float* s, const unsigned* p, float d) {
    uint4 u = *(const uint4*)p;
    s[0] = fmaf(bflo(u.x), d, s[0]); s[1] = fmaf(bfhi(u.x), d, s[1]);
    s[2] = fmaf(bflo(u.y), d, s[2]); s[3] = fmaf(bfhi(u.y), d, s[3]);
    s[4] = fmaf(bflo(u.z), d, s[4]); s[5] = fmaf(bfhi(u.z), d, s[5]);
    s[6] = fmaf(bflo(u.w), d, s[6]); s[7] = fmaf(bfhi(u.w), d, s[7]);
}

// ---------------- zero bucket cursors ----------------
__global__ void k_zero(int* __restrict__ p, int n) {
    int i = blockIdx.x * blockDim.x + threadIdx.x;
    if (i < n) p[i] = 0;
}

// ---------------- mega: bucket pass || xw1 GEMM (fused cast) || cast W2 -----
__global__ __launch_bounds__(256) void k_mega(
        const int* __restrict__ src, const int* __restrict__ dst,
        int* __restrict__ bcur, int* __restrict__ bstore,
        const float* __restrict__ x, const float* __restrict__ W1,
        const float* __restrict__ W2,
        unsigned short* __restrict__ w2bf, unsigned short* __restrict__ h1b) {
    __shared__ int hist[NBK];
    __shared__ int lcur[NBK];
    __shared__ int gpos[NBK];
    __shared__ int stage[TILE];
    __shared__ unsigned short bid[TILE];

    int tid = threadIdx.x;

    if (blockIdx.x < NBT) {
        // ---- role A: LDS-aggregated bucketing of edges by dst>>8 ----
        for (int i = tid; i < NBK; i += 256) hist[i] = 0;
        __syncthreads();

        int base = blockIdx.x * TILE;
        int p[16]; unsigned short bb[16];
#pragma unroll
        for (int k = 0; k < 16; ++k) {
            int e = base + k * 256 + tid;
            if (e < NE) {
                int d = dst[e], s = src[e];
                bb[k] = (unsigned short)(d >> 8);
                p[k]  = ((d & 255) << 24) | s;       // src < 2^24
                atomicAdd(&hist[bb[k]], 1);
            } else bb[k] = 0xFFFF;
        }
        __syncthreads();

        for (int i = tid; i < NBK; i += 256)
            gpos[i] = atomicAdd(&bcur[i], hist[i]);
        __syncthreads();

        if (tid < 64) {  // exclusive scan of hist (wave 0)
            int carry = 0;
            for (int c = 0; c < (NBK + 63) / 64; ++c) {
                int idx = c * 64 + tid;
                int v = (idx < NBK) ? hist[idx] : 0;
                int inc = v;
#pragma unroll
                for (int o = 1; o < 64; o <<= 1) {
                    int u = __shfl_up(inc, o, 64);
                    if (tid >= o) inc += u;
                }
                int tot = __shfl(inc, 63, 64);
                if (idx < NBK) { int ex = carry + inc - v; hist[idx] = ex; lcur[idx] = ex; }
                carry += tot;
            }
        }
        __syncthreads();

#pragma unroll
        for (int k = 0; k < 16; ++k) {
            if (bb[k] != 0xFFFF) {
                int lp = atomicAdd(&lcur[bb[k]], 1);
                stage[lp] = p[k];
                bid[lp] = bb[k];
            }
        }
        __syncthreads();

        int tcnt = min(TILE, NE - base);
        for (int i = tid; i < tcnt; i += 256) {
            int b = bid[i];
            int off = gpos[b] + (i - hist[b]);
            if (off < BCAP) bstore[b * BCAP + off] = stage[i];
        }
    } else if (blockIdx.x == NBT) {
        // ---- role B: cast W2 -> bf16 (W1 is converted in-reg by role C) ----
        for (int i = tid; i < DH * DO; i += 256) w2bf[i] = f2bf(W2[i]);
    } else {
        // ---- role C: h1b = bf16(x @ W1), fp32 inputs cast in-register ----
        int wave = tid >> 6, lane = tid & 63;
        int q = lane >> 4, m = lane & 15, o0 = wave * 16;
        int nb = (blockIdx.x - XW1_BASE) * 64;

        short8 bfr[4];  // B-frags for all 4 K-blocks (fp32 W1 -> bf16)
#pragma unroll
        for (int kb = 0; kb < 4; ++kb)
#pragma unroll
            for (int j = 0; j < 8; ++j)
                bfr[kb][j] = (short)f2bf(W1[(kb * 32 + q * 8 + j) * DH + o0 + m]);

#pragma unroll
        for (int mt = 0; mt < 4; ++mt) {
            int row = min(nb + mt * 16 + m, NN - 1);   // clamp overhang rows
            const float* xr = x + (size_t)row * DI;
            f32x4 acc = {0.f, 0.f, 0.f, 0.f};
#pragma unroll
            for (int kb = 0; kb < 4; ++kb) {
                f32x4 u0 = *(const f32x4*)(xr + kb * 32 + q * 8);
                f32x4 u1 = *(const f32x4*)(xr + kb * 32 + q * 8 + 4);
                short8 a;
                a[0] = (short)f2bf(u0.x); a[1] = (short)f2bf(u0.y);
                a[2] = (short)f2bf(u0.z); a[3] = (short)f2bf(u0.w);
                a[4] = (short)f2bf(u1.x); a[5] = (short)f2bf(u1.y);
                a[6] = (short)f2bf(u1.z); a[7] = (short)f2bf(u1.w);
                acc = __builtin_amdgcn_mfma_f32_16x16x32_bf16(a, bfr[kb], acc, 0, 0, 0);
            }
#pragma unroll
            for (int r = 0; r < 4; ++r) {
                int n = nb + mt * 16 + q * 4 + r;
                if (n < NN) h1b[(size_t)n * DH + o0 + m] = f2bf(acc[r]);  // unscaled
            }
        }
    }
}

// ---------------- per-bucket counting sort -> global CSR (512 thr) ----------
// Scatter goes straight to csr[] (L2-resident 36KB window); no sorted[] LDS.
__global__ __launch_bounds__(512) void k_bsort(
        const int* __restrict__ bcur, const int* __restrict__ bstore,
        int* __restrict__ csr,
        int* __restrict__ rpb, int* __restrict__ rpe, float* __restrict__ dinv) {
    __shared__ int buf[BCAP];
    __shared__ int hist[256], scan[256], cur[256];

    int b = blockIdx.x, tid = threadIdx.x;
    int cnt = min(bcur[b], BCAP);
    int base = b * BCAP;
    for (int i = tid; i < cnt; i += 512) buf[i] = bstore[base + i];
    if (tid < 256) hist[tid] = 0;
    __syncthreads();
    for (int i = tid; i < cnt; i += 512)
        atomicAdd(&hist[((unsigned)buf[i]) >> 24], 1);
    __syncthreads();

    if (tid < 64) {  // exclusive scan of 256 bins (wave 0)
        int carry = 0;
        for (int c = 0; c < 4; ++c) {
            int idx = c * 64 + tid;
            int v = hist[idx];
            int inc = v;
#pragma unroll
            for (int o = 1; o < 64; o <<= 1) {
                int u = __shfl_up(inc, o, 64);
                if (tid >= o) inc += u;
            }
            int tot = __shfl(inc, 63, 64);
            scan[idx] = carry + inc - v;
            cur[idx]  = carry + inc - v;
            carry += tot;
        }
    }
    __syncthreads();

    if (tid < 256) {
        int n = b * 256 + tid;
        if (n < NN) {
            int beg = base + scan[tid];
            rpb[n] = beg;
            rpe[n] = beg + hist[tid];
            dinv[n] = rsqrtf(1.0f + (float)hist[tid]);
        }
    }

    for (int i = tid; i < cnt; i += 512) {
        unsigned pv = (unsigned)buf[i];
        int pos = atomicAdd(&cur[pv >> 24], 1);
        csr[base + pos] = (int)(pv & 0xFFFFFF);
    }
}

// ---------------- gather layer 1 (uint4 loads, per-edge dinv[src]) ----------
// Wave = 1 node. lane = 8*q + f8: q = edge-slot group (8 slots/iter),
// f8 = uint4 index (features 8f8..8f8+7). Row = 32 uints = 8 uint4.
__global__ __launch_bounds__(256) void k_gather64(
        const int* __restrict__ rpb, const int* __restrict__ rpe,
        const int* __restrict__ csr, const unsigned* __restrict__ h,
        const float* __restrict__ dinv, const float* __restrict__ b1,
        unsigned* __restrict__ tbf) {
    int wave = threadIdx.x >> 6, lane = threadIdx.x & 63;
    int q = lane >> 3, f8 = lane & 7;
    int n = blockIdx.x * 4 + wave;
    int beg = rpb[n], end = rpe[n];
    float dn = dinv[n];

    float s[8] = {0.f, 0.f, 0.f, 0.f, 0.f, 0.f, 0.f, 0.f};
    if (q == 0)                          // self-loop: dinv[n]*h1[n]
        acc_row8(s, h + (size_t)n * 32 + 4 * f8, dn);

    for (int c = beg; c < end; c += 64) {
        int cnt = min(64, end - c);
        int sidx = (lane < cnt) ? csr[c + lane] : 0;
        int j = 0;
        for (; j + 16 <= cnt; j += 16) {   // 16 edges/iter, 2x16B loads/lane
            int sa = __shfl(sidx, j + q, 64);
            int sb = __shfl(sidx, j + 8 + q, 64);
            float da = dinv[sa], db = dinv[sb];
            acc_row8(s, h + (size_t)sa * 32 + 4 * f8, da);
            acc_row8(s, h + (size_t)sb * 32 + 4 * f8, db);
        }
        for (; j < cnt; j += 8) {          // tail, predicated
            int slot = j + q;              // j<=56, q<=7 -> slot<=63, shfl safe
            int sidx2 = __shfl(sidx, slot, 64);
            if (slot < cnt)
                acc_row8(s, h + (size_t)sidx2 * 32 + 4 * f8, dinv[sidx2]);
        }
    }
#pragma unroll
    for (int r = 0; r < 8; ++r) {
        s[r] += __shfl_xor(s[r], 8, 64);
        s[r] += __shfl_xor(s[r], 16, 64);
        s[r] += __shfl_xor(s[r], 32, 64);
    }
    if (q == 0) {
        float t[8];
#pragma unroll
        for (int r = 0; r < 8; ++r)
            t[r] = fmaxf(fmaf(s[r], dn, b1[8 * f8 + r]), 0.f);
        uint4 o;
        o.x = (unsigned)f2bf(t[0]) | ((unsigned)f2bf(t[1]) << 16);
        o.y = (unsigned)f2bf(t[2]) | ((unsigned)f2bf(t[3]) << 16);
        o.z = (unsigned)f2bf(t[4]) | ((unsigned)f2bf(t[5]) << 16);
        o.w = (unsigned)f2bf(t[6]) | ((unsigned)f2bf(t[7]) << 16);
        *(uint4*)(tbf + (size_t)n * 32 + 4 * f8) = o;
    }
}

// ---------------- layer 2 GEMM (MFMA): h2b = bf16((t @ W2) * dinv) ----------
__global__ __launch_bounds__(256) void k_l2_mfma(
        const unsigned short* __restrict__ tbf, const unsigned short* __restrict__ w2bf,
        const float* __restrict__ dinv, unsigned short* __restrict__ h2b) {
    int wave = threadIdx.x >> 6, lane = threadIdx.x & 63;
    int q = lane >> 4, m = lane & 15;
    int o0 = (wave & 1) * 16, mt = wave >> 1;
    int nb = blockIdx.x * 32;

    short8 bf[2];
#pragma unroll
    for (int kb = 0; kb < 2; ++kb)
#pragma unroll
        for (int j = 0; j < 8; ++j)
            bf[kb][j] = (short)w2bf[(kb * 32 + q * 8 + j) * DO + o0 + m];

    int row = nb + mt * 16 + m;
    f32x4 acc = {0.f, 0.f, 0.f, 0.f};
#pragma unroll
    for (int kb = 0; kb < 2; ++kb) {
        short8 a = *(const short8*)(tbf + (size_t)row * DH + kb * 32 + q * 8);
        acc = __builtin_amdgcn_mfma_f32_16x16x32_bf16(a, bf[kb], acc, 0, 0, 0);
    }
#pragma unroll
    for (int r = 0; r < 4; ++r) {
        int n = nb + mt * 16 + q * 4 + r;
        if (n < NN) h2b[(size_t)n * DO + o0 + m] = f2bf(acc[r] * dinv[n]);
    }
}

// ---------------- gather layer 2 (uint4 loads, 16-slot MLP) -----------------
// Wave = 1 node. lane = 4*q + fi: q = edge-slot group (16 slots/iter),
// fi = uint4 index (features 8fi..8fi+7). Row = 16 uints = 4 uint4.
__global__ __launch_bounds__(256) void k_gather32(
        const int* __restrict__ rpb, const int* __restrict__ rpe,
        const int* __restrict__ csr, const unsigned* __restrict__ h,
        const float* __restrict__ dinv, const float* __restrict__ b2,
        float* __restrict__ out) {
    int wave = threadIdx.x >> 6, lane = threadIdx.x & 63;
    int q = lane >> 2, fi = lane & 3;
    int n = blockIdx.x * 4 + wave;
    int beg = rpb[n], end = rpe[n];

    float s[8] = {0.f, 0.f, 0.f, 0.f, 0.f, 0.f, 0.f, 0.f};
    if (q == 0)                          // self-loop (h2b pre-scaled)
        acc_row8(s, h + (size_t)n * 16 + 4 * fi, 1.0f);

    for (int c = beg; c < end; c += 64) {
        int cnt = min(64, end - c);
        int sidx = (lane < cnt) ? csr[c + lane] : 0;
        int j = 0;
        for (; j + 32 <= cnt; j += 32) {   // 32 edges/iter, 2x16B loads/lane
            int sa = __shfl(sidx, j + q, 64);
            int sb = __shfl(sidx, j + 16 + q, 64);
            acc_row8(s, h + (size_t)sa * 16 + 4 * fi, 1.0f);
            acc_row8(s, h + (size_t)sb * 16 + 4 * fi, 1.0f);
        }
        for (; j < cnt; j += 16) {         // tail, predicated
            int slot = j + q;              // j<=48, q<=15 -> slot<=63, shfl safe
            int sidx2 = __shfl(sidx, slot, 64);
            if (slot < cnt)
                acc_row8(s, h + (size_t)sidx2 * 16 + 4 * fi, 1.0f);
        }
    }
#pragma unroll
    for (int r = 0; r < 8; ++r) {
        s[r] += __shfl_xor(s[r], 4, 64);
        s[r] += __shfl_xor(s[r], 8, 64);
        s[r] += __shfl_xor(s[r], 16, 64);
        s[r] += __shfl_xor(s[r], 32, 64);
    }
    if (q == 0) {
        float dn = dinv[n];
        float4 o0v, o1v;
        o0v.x = fmaf(s[0], dn, b2[8 * fi + 0]);
        o0v.y = fmaf(s[1], dn, b2[8 * fi + 1]);
        o0v.z = fmaf(s[2], dn, b2[8 * fi + 2]);
        o0v.w = fmaf(s[3], dn, b2[8 * fi + 3]);
        o1v.x = fmaf(s[4], dn, b2[8 * fi + 4]);
        o1v.y = fmaf(s[5], dn, b2[8 * fi + 5]);
        o1v.z = fmaf(s[6], dn, b2[8 * fi + 6]);
        o1v.w = fmaf(s[7], dn, b2[8 * fi + 7]);
        *(float4*)(out + (size_t)n * 32 + 8 * fi)     = o0v;
        *(float4*)(out + (size_t)n * 32 + 8 * fi + 4) = o1v;
    }
}

extern "C" void kernel_launch(void* const* d_in, const int* in_sizes, int n_in,
                              void* d_out, int out_size, void* d_ws, size_t ws_size,
                              hipStream_t stream) {
    const float* x  = (const float*)d_in[0];
    const float* W1 = (const float*)d_in[1];
    const float* b1 = (const float*)d_in[2];
    const float* W2 = (const float*)d_in[3];
    const float* b2 = (const float*)d_in[4];
    const int* ei  = (const int*)d_in[5];
    const int* src = ei;        // edge_index[0]
    const int* dst = ei + NE;   // edge_index[1]
    float* out = (float*)d_out;

    // workspace layout (4 B words), total 13,909,504 words = 55.6 MB:
    float* ws    = (float*)d_ws;
    int*   rpb   = (int*)ws;                          // 100,352
    int*   rpe   = (int*)(ws + 100352);               // 100,352
    float* dinv  = ws + 200704;                       // 100,352
    int*   bcur  = (int*)(ws + 301056);               // 512
    int*   bstor = (int*)(ws + 301568);               // 3,603,456
    int*   csr   = (int*)(ws + 3905024);              // 3,603,456
    unsigned short* w2bf = (unsigned short*)(ws + 7508480);   // 2,048 bf16 (1,024 w)
    unsigned short* tbf  = (unsigned short*)(ws + 7509504);   // 100,000x64 bf16 (3.2M w)
    unsigned short* h1b  = (unsigned short*)(ws + 10709504);  // 100,000x64 bf16 (3.2M w)
    unsigned short* h2b  = h1b;   // reuse (h1b dead after gather64); 100,000x32 bf16

    k_zero     <<<2, 256, 0, stream>>>(bcur, 512);
    k_mega     <<<XW1_BASE + XW1_BLOCKS, 256, 0, stream>>>(
                    src, dst, bcur, bstor, x, W1, W2, w2bf, h1b);
    k_bsort    <<<NBK, 512, 0, stream>>>(bcur, bstor, csr, rpb, rpe, dinv);

    k_gather64 <<<NN / 4, 256, 0, stream>>>(rpb, rpe, csr, (const unsigned*)h1b,
                                            dinv, b1, (unsigned*)tbf);
    k_l2_mfma  <<<NN / 32, 256, 0, stream>>>(tbf, w2bf, dinv, h2b);
    k_gather32 <<<NN / 4, 256, 0, stream>>>(rpb, rpe, csr, (const unsigned*)h2b,
                                            dinv, b2, out);
}